// Round 12
// baseline (150.572 us; speedup 1.0000x reference)
//
#include <hip/hip_runtime.h>
#include <hip/hip_bf16.h>

#define NODES 50000
#define EDGES 800000
#define FDIM  96
#define NCLS  40

// two-level counting sort geometry
#define NCHK 200                      // edge chunks (blocks)
#define CHKE 4000                     // EDGES / NCHK exactly
#define NB   196                      // coarse buckets of 256 nodes (dst>>8)
#define NCELL (NB * NCHK)             // 39200, layout [chunk][bucket]

#define WT_ELEMS (4 * 96 * 96)                 // 36864
#define WT_BLOCKS ((WT_ELEMS + 255) / 256)     // 144
#define F2B_N4 (NODES * FDIM / 4)              // 1200000
#define F2B_BLOCKS ((F2B_N4 + 255) / 256)      // 4688

typedef __attribute__((ext_vector_type(8))) short s8v;    // 8 bf16 MFMA A/B frag
typedef __attribute__((ext_vector_type(4))) float f32x4;  // MFMA C/D frag

__device__ __forceinline__ float b2f(ushort u) {
  unsigned int x = ((unsigned int)u) << 16;
  union { unsigned int i; float f; } c; c.i = x; return c.f;
}
__device__ __forceinline__ ushort f2b(float f) {
  __hip_bfloat16 b = __float2bfloat16(f);  // RNE
  return *reinterpret_cast<ushort*>(&b);
}

// ---------------- fused pass 1: per-chunk histogram (blocks 0..NCHK-1)
//                  + weight/feature bf16 prep (remaining blocks) ----------------

__global__ __launch_bounds__(256) void count_prep_kernel(const int* __restrict__ dst,
    int* __restrict__ cellCnt,
    const float* __restrict__ W1a, const float* __restrict__ W1b,
    const float* __restrict__ W2a, const float* __restrict__ W2b,
    const float* __restrict__ x,
    ushort* __restrict__ wt, ushort* __restrict__ xb) {
  int t = threadIdx.x;
  if (blockIdx.x < NCHK) {
    __shared__ int hist[NB];
    for (int i = t; i < NB; i += 256) hist[i] = 0;
    __syncthreads();
    int s = blockIdx.x * CHKE;
    for (int i = t; i < CHKE; i += 256) atomicAdd(&hist[dst[s + i] >> 8], 1);
    __syncthreads();
    for (int i = t; i < NB; i += 256) cellCnt[blockIdx.x * NB + i] = hist[i];  // coalesced
  } else if (blockIdx.x < NCHK + WT_BLOCKS) {
    int id = (blockIdx.x - NCHK) * 256 + t;
    if (id >= WT_ELEMS) return;
    int m = id / (96 * 96);
    int r = (id % (96 * 96)) / 96;  // output col n
    int k = id % 96;
    float v = 0.0f;
    if (m == 0) v = W1a[k * 96 + r];
    else if (m == 1) v = W1b[k * 96 + r];
    else if (m == 2) v = W2a[k * 96 + r];
    else if (r < NCLS) v = W2b[k * NCLS + r];
    wt[id] = f2b(v);
  } else {
    int i = (blockIdx.x - NCHK - WT_BLOCKS) * 256 + t;
    if (i < F2B_N4) {
      float4 v = ((const float4*)x)[i];
      ushort4 u;
      u.x = f2b(v.x); u.y = f2b(v.y); u.z = f2b(v.z); u.w = f2b(v.w);
      ((ushort4*)xb)[i] = u;
    }
  }
}

// ---------------- single-block cell scan ----------------
// cellCnt layout [chunk][bucket]: thread t (=bucket) streams column t with
// coalesced reads. Pass 1: per-bucket running offsets (pre-base) + totals;
// LDS exclusive scan over 196 totals; pass 2: add bucket base. Row 0 of
// cellOff then holds the bucket base offsets (used by bucket_sort).

__global__ __launch_bounds__(256) void cell_scan_kernel(const int* __restrict__ cellCnt,
                                                        int* __restrict__ cellOff) {
  __shared__ int sh[256];
  int t = threadIdx.x;
  int tot = 0;
  if (t < NB) {
    for (int c = 0; c < NCHK; ++c) {
      int v = cellCnt[c * NB + t];
      cellOff[c * NB + t] = tot;  // pre-base exclusive
      tot += v;
    }
  }
  sh[t] = (t < NB) ? tot : 0;
  __syncthreads();
#pragma unroll
  for (int d = 1; d < 256; d <<= 1) {
    int u = (t >= d) ? sh[t - d] : 0;
    __syncthreads();
    sh[t] += u;
    __syncthreads();
  }
  int base = sh[t] - tot;  // exclusive across buckets
  if (t < NB) {
    for (int c = 0; c < NCHK; ++c) cellOff[c * NB + t] += base;
  }
}

// pass B: scatter packed (fine<<16 | src) records into per-(bucket,chunk) runs.
__global__ __launch_bounds__(256) void bin_scatter_kernel(const int* __restrict__ src,
                                                          const int* __restrict__ dst,
                                                          const int* __restrict__ cellOff,
                                                          int* __restrict__ ebuf) {
  __shared__ int cur[NB];
  int t = threadIdx.x;
  for (int i = t; i < NB; i += 256) cur[i] = cellOff[blockIdx.x * NB + i];  // coalesced
  __syncthreads();
  int s = blockIdx.x * CHKE;
  for (int i = t; i < CHKE; i += 256) {
    int d = dst[s + i];
    int pos = atomicAdd(&cur[d >> 8], 1);
    ebuf[pos] = ((d & 255) << 16) | src[s + i];
  }
}

// pass C: per-bucket fine sort -> row_ptr + col(ushort)
__global__ __launch_bounds__(256) void bucket_sort_kernel(const int* __restrict__ ebuf,
                                                          const int* __restrict__ cellOff,
                                                          int* __restrict__ row_ptr,
                                                          ushort* __restrict__ col) {
  __shared__ int hist[256];
  __shared__ int sh[256];
  int b = blockIdx.x;
  int t = threadIdx.x;
  int s = cellOff[b];                                // bucket base (chunk-0 row)
  int e = (b + 1 < NB) ? cellOff[b + 1] : EDGES;
  hist[t] = 0;
  __syncthreads();
  for (int i = s + t; i < e; i += 256) atomicAdd(&hist[ebuf[i] >> 16], 1);
  __syncthreads();
  int v = hist[t];
  sh[t] = v;
  __syncthreads();
#pragma unroll
  for (int d = 1; d < 256; d <<= 1) {
    int u = (t >= d) ? sh[t - d] : 0;
    __syncthreads();
    sh[t] += u;
    __syncthreads();
  }
  int excl = sh[t] - v;
  int node = (b << 8) + t;
  if (node < NODES) row_ptr[node] = s + excl;
  if (node == NODES - 1) row_ptr[NODES] = EDGES;
  hist[t] = excl;  // reuse as cursor
  __syncthreads();
  for (int i = s + t; i < e; i += 256) {
    int ed = ebuf[i];
    int r = atomicAdd(&hist[ed >> 16], 1);
    col[s + r] = (ushort)(ed & 0xFFFF);
  }
}

// ---------------- aggregation (bf16 in/out, f32 accum) ----------------
// FULL WAVE per node, half-wave per contiguous edge-half. MASKED 8-way unroll:
// no serial tail — out-of-range edges clamp to t-1 (L1-hot re-read) and are
// zeroed via fmaf mask. Typical wave = ONE 24-load batch + shfl + store.

__global__ __launch_bounds__(256) void aggregate_kernel(const ushort* __restrict__ hin,
    const int* __restrict__ row_ptr, const ushort* __restrict__ col, ushort* __restrict__ z) {
  int gt = blockIdx.x * blockDim.x + threadIdx.x;
  int node = gt >> 6;
  if (node >= NODES) return;
  int lane = threadIdx.x & 63;
  int l = lane & 31;
  int h = lane >> 5;

  float a0 = 0.f, a1 = 0.f, a2 = 0.f;
  if (h == 0) {
    const ushort* self = hin + (size_t)node * FDIM;
    a0 = b2f(self[l]); a1 = b2f(self[l + 32]); a2 = b2f(self[l + 64]);
  }

  int e0 = row_ptr[node];
  int e1 = row_ptr[node + 1];
  int hl = (e1 - e0 + 1) >> 1;
  int e = e0 + h * hl;
  int t = h ? e1 : (e0 + hl);

  for (; e < t; e += 8) {
    const ushort* p8[8];
    float m[8];
#pragma unroll
    for (int q = 0; q < 8; ++q) {
      int idx = e + q;
      bool ok = idx < t;
      int c = col[ok ? idx : t - 1];
      p8[q] = hin + (size_t)c * FDIM;
      m[q] = ok ? 1.0f : 0.0f;
    }
    float s0 = 0.f, s1 = 0.f, s2 = 0.f;
#pragma unroll
    for (int q = 0; q < 8; ++q) {
      s0 = fmaf(m[q], b2f(p8[q][l]), s0);
      s1 = fmaf(m[q], b2f(p8[q][l + 32]), s1);
      s2 = fmaf(m[q], b2f(p8[q][l + 64]), s2);
    }
    a0 += s0; a1 += s1; a2 += s2;
  }

  a0 += __shfl_xor(a0, 32);
  a1 += __shfl_xor(a1, 32);
  a2 += __shfl_xor(a2, 32);

  if (h == 0) {
    ushort* zp = z + (size_t)node * FDIM;
    zp[l] = f2b(a0); zp[l + 32] = f2b(a1); zp[l + 64] = f2b(a2);
  }
}

// ---------------- fused GIN MLP: out = (relu(z@Wa+ba))@Wb+bb ----------------
// 64-row tile, 4 waves x 16 rows. Stage 1 LDS-free (A frags from global, Wa L1-hot);
// intermediate t staged bf16 in LDS [64][128] with XOR-16B swizzle; stage 2 reads
// A' frags from LDS, Wb from global. Frag maps (m89-verified):
// A row=lane&15, k=(lane>>4)*8+e; B col=lane&15 same k; C/D col=lane&15, row=(lane>>4)*4+j.

template <int NOUT2, bool RELU2, bool OUT_BF16>
__global__ __launch_bounds__(256) void gin_mlp_kernel(const ushort* __restrict__ A,
    const ushort* __restrict__ wtA, const float* __restrict__ biasA,
    const ushort* __restrict__ wtB, const float* __restrict__ biasB, void* __restrict__ outv) {
  constexpr int NT2 = (NOUT2 == 96) ? 6 : 3;
  __shared__ ushort sT[64 * 128];

  int lane = threadIdx.x & 63;
  int wave = threadIdx.x >> 6;
  int wrow0 = wave * 16;
  int node0 = blockIdx.x * 64;
  int r = lane & 15;
  int kq = lane >> 4;  // 0..3

  // stage 1: t = relu(z @ Wa + ba), 16 rows per wave
  int arow = node0 + wrow0 + r;
  if (arow >= NODES) arow = NODES - 1;  // clamp loads; stores guarded
  const ushort* ap = A + (size_t)arow * 96 + kq * 8;
  s8v a0 = *(const s8v*)(ap);
  s8v a1 = *(const s8v*)(ap + 32);
  s8v a2 = *(const s8v*)(ap + 64);

#pragma unroll
  for (int nt = 0; nt < 6; ++nt) {
    int colg = nt * 16 + r;
    const ushort* bp = wtA + (size_t)colg * 96 + kq * 8;
    s8v b0 = *(const s8v*)(bp);
    s8v b1 = *(const s8v*)(bp + 32);
    s8v b2 = *(const s8v*)(bp + 64);
    float bv = biasA[colg];
    f32x4 acc = {bv, bv, bv, bv};
    acc = __builtin_amdgcn_mfma_f32_16x16x32_bf16(a0, b0, acc, 0, 0, 0);
    acc = __builtin_amdgcn_mfma_f32_16x16x32_bf16(a1, b1, acc, 0, 0, 0);
    acc = __builtin_amdgcn_mfma_f32_16x16x32_bf16(a2, b2, acc, 0, 0, 0);
#pragma unroll
    for (int j = 0; j < 4; ++j) {
      int trow = wrow0 + kq * 4 + j;
      float v = fmaxf(acc[j], 0.0f);  // GIN MLP inner relu
      sT[(trow * 128) + (colg ^ ((trow & 7) << 3))] = f2b(v);
    }
  }
  __syncthreads();

  // stage 2: out = t @ Wb + bb
  int trow = wrow0 + r;
  int sbase = trow * 128;
  int swz = (trow & 7) << 3;
  s8v c0 = *(const s8v*)&sT[sbase + ((kq * 8 + 0)  ^ swz)];
  s8v c1 = *(const s8v*)&sT[sbase + ((kq * 8 + 32) ^ swz)];
  s8v c2 = *(const s8v*)&sT[sbase + ((kq * 8 + 64) ^ swz)];

#pragma unroll
  for (int nt = 0; nt < NT2; ++nt) {
    int colg = nt * 16 + r;
    const ushort* bp = wtB + (size_t)colg * 96 + kq * 8;
    s8v b0 = *(const s8v*)(bp);
    s8v b1 = *(const s8v*)(bp + 32);
    s8v b2 = *(const s8v*)(bp + 64);
    float bv = (colg < NOUT2) ? biasB[colg] : 0.0f;
    f32x4 acc = {bv, bv, bv, bv};
    acc = __builtin_amdgcn_mfma_f32_16x16x32_bf16(c0, b0, acc, 0, 0, 0);
    acc = __builtin_amdgcn_mfma_f32_16x16x32_bf16(c1, b1, acc, 0, 0, 0);
    acc = __builtin_amdgcn_mfma_f32_16x16x32_bf16(c2, b2, acc, 0, 0, 0);
#pragma unroll
    for (int j = 0; j < 4; ++j) {
      int grow = node0 + wrow0 + kq * 4 + j;
      if (grow < NODES && colg < NOUT2) {
        float v = acc[j];
        if (RELU2) v = fmaxf(v, 0.0f);
        if (OUT_BF16)
          ((ushort*)outv)[(size_t)grow * NOUT2 + colg] = f2b(v);
        else
          ((float*)outv)[(size_t)grow * NOUT2 + colg] = v;
      }
    }
  }
}

// ---------------- launch ----------------

extern "C" void kernel_launch(void* const* d_in, const int* in_sizes, int n_in,
                              void* d_out, int out_size, void* d_ws, size_t ws_size,
                              hipStream_t stream) {
  const float* x    = (const float*)d_in[0];
  const int*   ei   = (const int*)d_in[1];   // [2][E]
  const float* W1a  = (const float*)d_in[2];
  const float* b1a  = (const float*)d_in[3];
  const float* W1b  = (const float*)d_in[4];
  const float* b1b  = (const float*)d_in[5];
  const float* W2a  = (const float*)d_in[6];
  const float* b2a  = (const float*)d_in[7];
  const float* W2b  = (const float*)d_in[8];
  const float* b2b  = (const float*)d_in[9];
  float* out = (float*)d_out;

  const int* src = ei;
  const int* dst = ei + EDGES;

  char* ws = (char*)d_ws;
  size_t off = 0;
  auto alloc = [&](size_t bytes) {
    size_t p = off;
    off = (off + bytes + 255) & ~(size_t)255;
    return p;
  };
  int*  cellCnt  = (int*)(ws + alloc((size_t)NCELL * 4));
  int*  cellOff  = (int*)(ws + alloc((size_t)NCELL * 4));
  int*  row_ptr  = (int*)(ws + alloc((size_t)(NODES + 1) * 4));
  int*  ebuf     = (int*)(ws + alloc((size_t)EDGES * 4));
  ushort* col    = (ushort*)(ws + alloc((size_t)EDGES * 2));
  ushort* wt     = (ushort*)(ws + alloc((size_t)4 * 96 * 96 * 2));
  ushort* xb     = (ushort*)(ws + alloc((size_t)NODES * FDIM * 2));
  ushort* B1     = (ushort*)(ws + alloc((size_t)NODES * FDIM * 2));
  ushort* B2     = (ushort*)(ws + alloc((size_t)NODES * FDIM * 2));

  const int AGG_GRID  = (NODES * 64 + 255) / 256;  // 12500 (1 wave/node)
  const int GEMM_GRID = (NODES + 63) / 64;         // 782

  // pass 1: histogram (200 blocks) + weight/feature prep (rest) in ONE dispatch
  count_prep_kernel<<<NCHK + WT_BLOCKS + F2B_BLOCKS, 256, 0, stream>>>(
      dst, cellCnt, W1a, W1b, W2a, W2b, x, wt, xb);

  // CSR build: single-block scan + scatter + fine sort
  cell_scan_kernel<<<1, 256, 0, stream>>>(cellCnt, cellOff);
  bin_scatter_kernel<<<NCHK, 256, 0, stream>>>(src, dst, cellOff, ebuf);
  bucket_sort_kernel<<<NB, 256, 0, stream>>>(ebuf, cellOff, row_ptr, col);

  // layer 1: agg(xb)->B1; fused MLP -> B2 (= relu(h))
  aggregate_kernel<<<AGG_GRID, 256, 0, stream>>>(xb, row_ptr, col, B1);
  gin_mlp_kernel<96, true, true><<<GEMM_GRID, 256, 0, stream>>>(
      B1, wt + 0 * 9216, b1a, wt + 1 * 9216, b1b, B2);

  // layer 2: agg(B2)->B1; fused MLP -> out (f32)
  aggregate_kernel<<<AGG_GRID, 256, 0, stream>>>(B2, row_ptr, col, B1);
  gin_mlp_kernel<40, false, false><<<GEMM_GRID, 256, 0, stream>>>(
      B1, wt + 2 * 9216, b2a, wt + 3 * 9216, b2b, out);
}

// Round 13
// 119.378 us; speedup vs baseline: 1.2613x; 1.2613x over previous
//
#include <hip/hip_runtime.h>
#include <hip/hip_bf16.h>

#define NODES 50000
#define EDGES 800000
#define FDIM  96
#define NCLS  40

// two-level counting sort geometry
#define NCHK 200                      // edge chunks (blocks)
#define CHKE 4000                     // EDGES / NCHK exactly
#define NB   196                      // coarse buckets of 256 nodes (dst>>8)
#define NCELL (NB * NCHK)             // 39200, layout [bucket][chunk]
#define SCAN_BLOCKS ((NCELL + 255) / 256)  // 154

#define WT_ELEMS (4 * 96 * 96)                 // 36864
#define WT_BLOCKS ((WT_ELEMS + 255) / 256)     // 144
#define F2B_N4 (NODES * FDIM / 4)              // 1200000
#define F2B_BLOCKS ((F2B_N4 + 255) / 256)      // 4688

typedef __attribute__((ext_vector_type(8))) short s8v;    // 8 bf16 MFMA A/B frag
typedef __attribute__((ext_vector_type(4))) float f32x4;  // MFMA C/D frag

__device__ __forceinline__ float b2f(ushort u) {
  unsigned int x = ((unsigned int)u) << 16;
  union { unsigned int i; float f; } c; c.i = x; return c.f;
}
__device__ __forceinline__ ushort f2b(float f) {
  __hip_bfloat16 b = __float2bfloat16(f);  // RNE
  return *reinterpret_cast<ushort*>(&b);
}

// ---------------- fused pass 1: per-chunk histogram (blocks 0..NCHK-1)
//                  + weight/feature bf16 prep (remaining blocks) ----------------

__global__ __launch_bounds__(256) void count_prep_kernel(const int* __restrict__ dst,
    int* __restrict__ cellCnt,
    const float* __restrict__ W1a, const float* __restrict__ W1b,
    const float* __restrict__ W2a, const float* __restrict__ W2b,
    const float* __restrict__ x,
    ushort* __restrict__ wt, ushort* __restrict__ xb) {
  int t = threadIdx.x;
  if (blockIdx.x < NCHK) {
    __shared__ int hist[NB];
    for (int i = t; i < NB; i += 256) hist[i] = 0;
    __syncthreads();
    int s = blockIdx.x * CHKE;
    for (int i = t; i < CHKE; i += 256) atomicAdd(&hist[dst[s + i] >> 8], 1);
    __syncthreads();
    for (int i = t; i < NB; i += 256) cellCnt[i * NCHK + blockIdx.x] = hist[i];
  } else if (blockIdx.x < NCHK + WT_BLOCKS) {
    int id = (blockIdx.x - NCHK) * 256 + t;
    if (id >= WT_ELEMS) return;
    int m = id / (96 * 96);
    int r = (id % (96 * 96)) / 96;  // output col n
    int k = id % 96;
    float v = 0.0f;
    if (m == 0) v = W1a[k * 96 + r];
    else if (m == 1) v = W1b[k * 96 + r];
    else if (m == 2) v = W2a[k * 96 + r];
    else if (r < NCLS) v = W2b[k * NCLS + r];
    wt[id] = f2b(v);
  } else {
    int i = (blockIdx.x - NCHK - WT_BLOCKS) * 256 + t;
    if (i < F2B_N4) {
      float4 v = ((const float4*)x)[i];
      ushort4 u;
      u.x = f2b(v.x); u.y = f2b(v.y); u.z = f2b(v.z); u.w = f2b(v.w);
      ((ushort4*)xb)[i] = u;
    }
  }
}

// ---------------- generalized 3-stage exclusive scan over n ints ----------------

__global__ __launch_bounds__(256) void partial_kernel(const int* __restrict__ a, int n,
                                                      int* __restrict__ partials) {
  __shared__ int sh[256];
  int t = threadIdx.x;
  int idx = blockIdx.x * 256 + t;
  int v = (idx < n) ? a[idx] : 0;
  sh[t] = v;
  __syncthreads();
#pragma unroll
  for (int d = 1; d < 256; d <<= 1) {
    int u = (t >= d) ? sh[t - d] : 0;
    __syncthreads();
    sh[t] += u;
    __syncthreads();
  }
  if (t == 255) partials[blockIdx.x] = sh[255];
}

__global__ __launch_bounds__(256) void scan_partials_kernel(const int* __restrict__ partials,
                                                            int nb, int* __restrict__ poffs) {
  __shared__ int sh[256];
  int t = threadIdx.x;
  int v = (t < nb) ? partials[t] : 0;
  sh[t] = v;
  __syncthreads();
#pragma unroll
  for (int d = 1; d < 256; d <<= 1) {
    int u = (t >= d) ? sh[t - d] : 0;
    __syncthreads();
    sh[t] += u;
    __syncthreads();
  }
  if (t < nb) poffs[t] = sh[t] - v;  // exclusive
}

__global__ __launch_bounds__(256) void final_scan_kernel(const int* __restrict__ a, int n,
                                                         const int* __restrict__ poffs,
                                                         int* __restrict__ out) {
  __shared__ int sh[256];
  int t = threadIdx.x;
  int idx = blockIdx.x * 256 + t;
  int v = (idx < n) ? a[idx] : 0;
  sh[t] = v;
  __syncthreads();
#pragma unroll
  for (int d = 1; d < 256; d <<= 1) {
    int u = (t >= d) ? sh[t - d] : 0;
    __syncthreads();
    sh[t] += u;
    __syncthreads();
  }
  if (idx < n) out[idx] = poffs[blockIdx.x] + sh[t] - v;
}

// pass B: scatter packed (fine<<16 | src) records into per-(bucket,chunk) runs.
__global__ __launch_bounds__(256) void bin_scatter_kernel(const int* __restrict__ src,
                                                          const int* __restrict__ dst,
                                                          const int* __restrict__ cellOff,
                                                          int* __restrict__ ebuf) {
  __shared__ int cur[NB];
  int t = threadIdx.x;
  for (int i = t; i < NB; i += 256) cur[i] = cellOff[i * NCHK + blockIdx.x];
  __syncthreads();
  int s = blockIdx.x * CHKE;
  for (int i = t; i < CHKE; i += 256) {
    int d = dst[s + i];
    int pos = atomicAdd(&cur[d >> 8], 1);
    ebuf[pos] = ((d & 255) << 16) | src[s + i];
  }
}

// pass C: per-bucket fine sort -> row_ptr + col(ushort)
__global__ __launch_bounds__(256) void bucket_sort_kernel(const int* __restrict__ ebuf,
                                                          const int* __restrict__ cellOff,
                                                          int* __restrict__ row_ptr,
                                                          ushort* __restrict__ col) {
  __shared__ int hist[256];
  __shared__ int sh[256];
  int b = blockIdx.x;
  int t = threadIdx.x;
  int s = cellOff[b * NCHK];
  int e = (b + 1 < NB) ? cellOff[(b + 1) * NCHK] : EDGES;
  hist[t] = 0;
  __syncthreads();
  for (int i = s + t; i < e; i += 256) atomicAdd(&hist[ebuf[i] >> 16], 1);
  __syncthreads();
  int v = hist[t];
  sh[t] = v;
  __syncthreads();
#pragma unroll
  for (int d = 1; d < 256; d <<= 1) {
    int u = (t >= d) ? sh[t - d] : 0;
    __syncthreads();
    sh[t] += u;
    __syncthreads();
  }
  int excl = sh[t] - v;
  int node = (b << 8) + t;
  if (node < NODES) row_ptr[node] = s + excl;
  if (node == NODES - 1) row_ptr[NODES] = EDGES;
  hist[t] = excl;  // reuse as cursor
  __syncthreads();
  for (int i = s + t; i < e; i += 256) {
    int ed = ebuf[i];
    int r = atomicAdd(&hist[ed >> 16], 1);
    col[s + r] = (ushort)(ed & 0xFFFF);
  }
}

// ---------------- aggregation (bf16 in/out, f32 accum) ----------------
// FULL WAVE per node, half-wave per contiguous edge-half. MASKED 8-way unroll:
// no serial tail — out-of-range edges clamp to t-1 (L1-hot re-read) and are
// zeroed via fmaf mask. Typical wave = ONE 24-load batch + shfl + store.

__global__ __launch_bounds__(256) void aggregate_kernel(const ushort* __restrict__ hin,
    const int* __restrict__ row_ptr, const ushort* __restrict__ col, ushort* __restrict__ z) {
  int gt = blockIdx.x * blockDim.x + threadIdx.x;
  int node = gt >> 6;
  if (node >= NODES) return;
  int lane = threadIdx.x & 63;
  int l = lane & 31;
  int h = lane >> 5;

  float a0 = 0.f, a1 = 0.f, a2 = 0.f;
  if (h == 0) {
    const ushort* self = hin + (size_t)node * FDIM;
    a0 = b2f(self[l]); a1 = b2f(self[l + 32]); a2 = b2f(self[l + 64]);
  }

  int e0 = row_ptr[node];
  int e1 = row_ptr[node + 1];
  int hl = (e1 - e0 + 1) >> 1;
  int e = e0 + h * hl;
  int t = h ? e1 : (e0 + hl);

  for (; e < t; e += 8) {
    const ushort* p8[8];
    float m[8];
#pragma unroll
    for (int q = 0; q < 8; ++q) {
      int idx = e + q;
      bool ok = idx < t;
      int c = col[ok ? idx : t - 1];
      p8[q] = hin + (size_t)c * FDIM;
      m[q] = ok ? 1.0f : 0.0f;
    }
    float s0 = 0.f, s1 = 0.f, s2 = 0.f;
#pragma unroll
    for (int q = 0; q < 8; ++q) {
      s0 = fmaf(m[q], b2f(p8[q][l]), s0);
      s1 = fmaf(m[q], b2f(p8[q][l + 32]), s1);
      s2 = fmaf(m[q], b2f(p8[q][l + 64]), s2);
    }
    a0 += s0; a1 += s1; a2 += s2;
  }

  a0 += __shfl_xor(a0, 32);
  a1 += __shfl_xor(a1, 32);
  a2 += __shfl_xor(a2, 32);

  if (h == 0) {
    ushort* zp = z + (size_t)node * FDIM;
    zp[l] = f2b(a0); zp[l + 32] = f2b(a1); zp[l + 64] = f2b(a2);
  }
}

// ---------------- fused GIN MLP: out = (relu(z@Wa+ba))@Wb+bb ----------------
// 64-row tile, 4 waves x 16 rows. Stage 1 LDS-free (A frags from global, Wa L1-hot);
// intermediate t staged bf16 in LDS [64][128] with XOR-16B swizzle; stage 2 reads
// A' frags from LDS, Wb from global. Frag maps (m89-verified):
// A row=lane&15, k=(lane>>4)*8+e; B col=lane&15 same k; C/D col=lane&15, row=(lane>>4)*4+j.

template <int NOUT2, bool RELU2, bool OUT_BF16>
__global__ __launch_bounds__(256) void gin_mlp_kernel(const ushort* __restrict__ A,
    const ushort* __restrict__ wtA, const float* __restrict__ biasA,
    const ushort* __restrict__ wtB, const float* __restrict__ biasB, void* __restrict__ outv) {
  constexpr int NT2 = (NOUT2 == 96) ? 6 : 3;
  __shared__ ushort sT[64 * 128];

  int lane = threadIdx.x & 63;
  int wave = threadIdx.x >> 6;
  int wrow0 = wave * 16;
  int node0 = blockIdx.x * 64;
  int r = lane & 15;
  int kq = lane >> 4;  // 0..3

  // stage 1: t = relu(z @ Wa + ba), 16 rows per wave
  int arow = node0 + wrow0 + r;
  if (arow >= NODES) arow = NODES - 1;  // clamp loads; stores guarded
  const ushort* ap = A + (size_t)arow * 96 + kq * 8;
  s8v a0 = *(const s8v*)(ap);
  s8v a1 = *(const s8v*)(ap + 32);
  s8v a2 = *(const s8v*)(ap + 64);

#pragma unroll
  for (int nt = 0; nt < 6; ++nt) {
    int colg = nt * 16 + r;
    const ushort* bp = wtA + (size_t)colg * 96 + kq * 8;
    s8v b0 = *(const s8v*)(bp);
    s8v b1 = *(const s8v*)(bp + 32);
    s8v b2 = *(const s8v*)(bp + 64);
    float bv = biasA[colg];
    f32x4 acc = {bv, bv, bv, bv};
    acc = __builtin_amdgcn_mfma_f32_16x16x32_bf16(a0, b0, acc, 0, 0, 0);
    acc = __builtin_amdgcn_mfma_f32_16x16x32_bf16(a1, b1, acc, 0, 0, 0);
    acc = __builtin_amdgcn_mfma_f32_16x16x32_bf16(a2, b2, acc, 0, 0, 0);
#pragma unroll
    for (int j = 0; j < 4; ++j) {
      int trow = wrow0 + kq * 4 + j;
      float v = fmaxf(acc[j], 0.0f);  // GIN MLP inner relu
      sT[(trow * 128) + (colg ^ ((trow & 7) << 3))] = f2b(v);
    }
  }
  __syncthreads();

  // stage 2: out = t @ Wb + bb
  int trow = wrow0 + r;
  int sbase = trow * 128;
  int swz = (trow & 7) << 3;
  s8v c0 = *(const s8v*)&sT[sbase + ((kq * 8 + 0)  ^ swz)];
  s8v c1 = *(const s8v*)&sT[sbase + ((kq * 8 + 32) ^ swz)];
  s8v c2 = *(const s8v*)&sT[sbase + ((kq * 8 + 64) ^ swz)];

#pragma unroll
  for (int nt = 0; nt < NT2; ++nt) {
    int colg = nt * 16 + r;
    const ushort* bp = wtB + (size_t)colg * 96 + kq * 8;
    s8v b0 = *(const s8v*)(bp);
    s8v b1 = *(const s8v*)(bp + 32);
    s8v b2 = *(const s8v*)(bp + 64);
    float bv = (colg < NOUT2) ? biasB[colg] : 0.0f;
    f32x4 acc = {bv, bv, bv, bv};
    acc = __builtin_amdgcn_mfma_f32_16x16x32_bf16(c0, b0, acc, 0, 0, 0);
    acc = __builtin_amdgcn_mfma_f32_16x16x32_bf16(c1, b1, acc, 0, 0, 0);
    acc = __builtin_amdgcn_mfma_f32_16x16x32_bf16(c2, b2, acc, 0, 0, 0);
#pragma unroll
    for (int j = 0; j < 4; ++j) {
      int grow = node0 + wrow0 + kq * 4 + j;
      if (grow < NODES && colg < NOUT2) {
        float v = acc[j];
        if (RELU2) v = fmaxf(v, 0.0f);
        if (OUT_BF16)
          ((ushort*)outv)[(size_t)grow * NOUT2 + colg] = f2b(v);
        else
          ((float*)outv)[(size_t)grow * NOUT2 + colg] = v;
      }
    }
  }
}

// ---------------- launch ----------------

extern "C" void kernel_launch(void* const* d_in, const int* in_sizes, int n_in,
                              void* d_out, int out_size, void* d_ws, size_t ws_size,
                              hipStream_t stream) {
  const float* x    = (const float*)d_in[0];
  const int*   ei   = (const int*)d_in[1];   // [2][E]
  const float* W1a  = (const float*)d_in[2];
  const float* b1a  = (const float*)d_in[3];
  const float* W1b  = (const float*)d_in[4];
  const float* b1b  = (const float*)d_in[5];
  const float* W2a  = (const float*)d_in[6];
  const float* b2a  = (const float*)d_in[7];
  const float* W2b  = (const float*)d_in[8];
  const float* b2b  = (const float*)d_in[9];
  float* out = (float*)d_out;

  const int* src = ei;
  const int* dst = ei + EDGES;

  char* ws = (char*)d_ws;
  size_t off = 0;
  auto alloc = [&](size_t bytes) {
    size_t p = off;
    off = (off + bytes + 255) & ~(size_t)255;
    return p;
  };
  int*  cellCnt  = (int*)(ws + alloc((size_t)NCELL * 4));
  int*  cellOff  = (int*)(ws + alloc((size_t)NCELL * 4));
  int*  partials = (int*)(ws + alloc((size_t)SCAN_BLOCKS * 4));
  int*  poffs    = (int*)(ws + alloc((size_t)SCAN_BLOCKS * 4));
  int*  row_ptr  = (int*)(ws + alloc((size_t)(NODES + 1) * 4));
  int*  ebuf     = (int*)(ws + alloc((size_t)EDGES * 4));
  ushort* col    = (ushort*)(ws + alloc((size_t)EDGES * 2));
  ushort* wt     = (ushort*)(ws + alloc((size_t)4 * 96 * 96 * 2));
  ushort* xb     = (ushort*)(ws + alloc((size_t)NODES * FDIM * 2));
  ushort* B1     = (ushort*)(ws + alloc((size_t)NODES * FDIM * 2));
  ushort* B2     = (ushort*)(ws + alloc((size_t)NODES * FDIM * 2));

  const int AGG_GRID  = (NODES * 64 + 255) / 256;  // 12500 (1 wave/node)
  const int GEMM_GRID = (NODES + 63) / 64;         // 782

  // pass 1: histogram (200 blocks) + weight/feature prep (rest) in ONE dispatch
  count_prep_kernel<<<NCHK + WT_BLOCKS + F2B_BLOCKS, 256, 0, stream>>>(
      dst, cellCnt, W1a, W1b, W2a, W2b, x, wt, xb);

  // CSR build: scan + scatter + fine sort
  partial_kernel<<<SCAN_BLOCKS, 256, 0, stream>>>(cellCnt, NCELL, partials);
  scan_partials_kernel<<<1, 256, 0, stream>>>(partials, SCAN_BLOCKS, poffs);
  final_scan_kernel<<<SCAN_BLOCKS, 256, 0, stream>>>(cellCnt, NCELL, poffs, cellOff);
  bin_scatter_kernel<<<NCHK, 256, 0, stream>>>(src, dst, cellOff, ebuf);
  bucket_sort_kernel<<<NB, 256, 0, stream>>>(ebuf, cellOff, row_ptr, col);

  // layer 1: agg(xb)->B1; fused MLP -> B2 (= relu(h))
  aggregate_kernel<<<AGG_GRID, 256, 0, stream>>>(xb, row_ptr, col, B1);
  gin_mlp_kernel<96, true, true><<<GEMM_GRID, 256, 0, stream>>>(
      B1, wt + 0 * 9216, b1a, wt + 1 * 9216, b1b, B2);

  // layer 2: agg(B2)->B1; fused MLP -> out (f32)
  aggregate_kernel<<<AGG_GRID, 256, 0, stream>>>(B2, row_ptr, col, B1);
  gin_mlp_kernel<40, false, false><<<GEMM_GRID, 256, 0, stream>>>(
      B1, wt + 2 * 9216, b2a, wt + 3 * 9216, b2b, out);
}